// Round 3
// baseline (1107.061 us; speedup 1.0000x reference)
//
#include <hip/hip_runtime.h>
#include <hip/hip_bf16.h>

#define BB 256
#define NN 257
#define NT 256   // tokens per batch (N-1)
#define DD 768
#define KC 8     // K clusters
#define VV 10000
#define ITERS 4

#define CH 8                 // tokens per chunk
#define NCHUNK (NT / CH)     // 32 chunks per iteration
#define PADD 772             // padded row stride (dwords); 772*4 B is 16B-aligned

__device__ __forceinline__ float waveReduceSum(float v) {
#pragma unroll
    for (int off = 32; off > 0; off >>= 1)
        v += __shfl_xor(v, off, 64);
    return v;
}

// One block (1024 threads, 16 waves) per batch. Tokens are streamed from HBM
// exactly ONCE per k-means iteration via coalesced float4 staging into LDS;
// a 4-deep software pipeline (stage s | sim s-1 | mask s-2 | acc s-3) with one
// barrier per step overlaps HBM, LDS-read sim, and VALU accumulate.
// All per-value fp chains are bit-identical to the round-1 kernel that passed:
//  - sim: per-(token,row) 192-step float4 fma chain, j ascending
//  - c1/tsum: per-(dim[,cluster]) sequential adds, n ascending (chunks in order)
//  - norms: wave-per-row 12-step fma + 64-lane butterfly
__global__ __launch_bounds__(1024) void kmeans_kernel(
    const float* __restrict__ tokens,
    const float* __restrict__ vc,
    const int* __restrict__ topk,
    float* __restrict__ out_assign,   // (B, 256, 8) float
    float* __restrict__ delta)        // (V) float accumulators (pre-zeroed)
{
    __shared__ float cent[16][PADD];          // 49.4 KB normalized centroids (row = 2k+c)
    __shared__ float bufs[4][CH][PADD];       // 98.8 KB rotating token chunks
    __shared__ float simbuf[2][CH][17];       // 1.1 KB  sim values (tok, row)
    __shared__ float tsum[DD];                // 3 KB
    __shared__ unsigned maskA[NT];            // 1 KB
    __shared__ int sidx[KC];

    float* c1o = &bufs[0][0][0];              // overlay: c1buf[8][PADD] over bufs[0]

    const int b = blockIdx.x;
    const int t = threadIdx.x;
    const int lane = t & 63;
    const int wave = t >> 6;

    if (t < KC) sidx[t] = topk[b * KC + t];
    __syncthreads();

    // ---- gather + L2-normalize 16 initial centroid rows: wave r -> row r
    {
        const int r = wave;
        const int k = r >> 1, c = r & 1;
        const float* src = vc + ((size_t)sidx[k] * 2 + c) * DD;
        float vals[12];
        float ss = 0.f;
#pragma unroll
        for (int j = 0; j < 12; ++j) {
            vals[j] = src[lane + 64 * j];
            ss = fmaf(vals[j], vals[j], ss);
        }
        ss = waveReduceSum(ss);
        float iv = 1.0f / fmaxf(sqrtf(ss), 1e-12f);
#pragma unroll
        for (int j = 0; j < 12; ++j)
            cent[r][lane + 64 * j] = vals[j] * iv;
    }
    __syncthreads();

    const float* tpb = tokens + ((size_t)b * NN + 1) * DD;

    // role constants
    const int q  = t - 256;                 // acc/stage thread id (0..767) when t>=256
    const int r0 = (q >= 0) ? (q / 192) : 0;       // stage row for f4 = q
    const int c0 = (q >= 0) ? (q - r0 * 192) : 0;  // stage col4
    const int simtok = t & 7;               // sim: token in chunk
    const int simrow = (t >> 3) & 15;       // sim: centroid row

    float treg = 0.f;                       // tsum accumulator (iter 0, acc threads)

    for (int it = 0; it < ITERS; ++it) {
        float c1r[KC];
#pragma unroll
        for (int k = 0; k < KC; ++k) c1r[k] = 0.f;

        const int NSTEP = NCHUNK + 3;       // 35
        for (int s = 0; s < NSTEP; ++s) {
            if (t >= 256) {
                // ---- stage chunk s: issue global loads first (latency hidden by acc)
                float4 g0, g1;
                if (s < NCHUNK) {
                    const float* gp = tpb + (size_t)s * CH * DD;
                    g0 = *(const float4*)(gp + 4 * q);
                    g1 = *(const float4*)(gp + 4 * (q + 768));
                }
                // ---- accumulate chunk s-3
                if (s >= 3) {
                    const int cix = s - 3;
                    const float* bp = &bufs[cix & 3][0][0];
#pragma unroll
                    for (int i = 0; i < CH; ++i) {
                        unsigned mn = maskA[cix * CH + i];     // LDS broadcast
                        float v = bp[i * PADD + q];            // stride-1, 2-way (free)
#pragma unroll
                        for (int k = 0; k < KC; ++k)
                            c1r[k] += ((mn >> k) & 1) ? v : 0.f;
                        if (it == 0) treg += v;
                    }
                }
                // ---- commit staged chunk to LDS
                if (s < NCHUNK) {
                    float* wp = &bufs[s & 3][0][0];
                    *(float4*)(wp + r0 * PADD + c0 * 4)       = g0;
                    *(float4*)(wp + (r0 + 4) * PADD + c0 * 4) = g1;
                }
            } else if (t < 128) {
                // ---- sim chunk s-1: thread (tok, row), full fma chain
                if (s >= 1 && s <= NCHUNK) {
                    const int cix = s - 1;
                    const float* bp = &bufs[cix & 3][simtok][0];
                    const float* cp = &cent[simrow][0];
                    float acc = 0.f;
#pragma unroll 2
                    for (int j = 0; j < DD; j += 4) {
                        float4 a  = *(const float4*)(bp + j);
                        float4 cv = *(const float4*)(cp + j);
                        acc = fmaf(a.w, cv.w, fmaf(a.z, cv.z,
                               fmaf(a.y, cv.y, fmaf(a.x, cv.x, acc))));
                    }
                    simbuf[cix & 1][simtok][simrow] = acc;
                }
            } else if (t < 128 + CH) {
                // ---- mask chunk s-2 (+ assignment write on last iter)
                if (s >= 2 && s <= NCHUNK + 1) {
                    const int cix = s - 2;
                    const int i = t - 128;
                    const float* sv = &simbuf[cix & 1][i][0];
                    unsigned m = 0;
#pragma unroll
                    for (int k = 0; k < KC; ++k)
                        if (sv[2 * k + 1] > sv[2 * k]) m |= (1u << k);
                    const int n = cix * CH + i;
                    maskA[n] = m;
                    if (it == ITERS - 1) {
                        float4* op = (float4*)(out_assign + ((size_t)b * NT + n) * KC);
                        op[0] = make_float4((m & 1) ? 1.f : 0.f, (m & 2) ? 1.f : 0.f,
                                            (m & 4) ? 1.f : 0.f, (m & 8) ? 1.f : 0.f);
                        op[1] = make_float4((m & 16) ? 1.f : 0.f, (m & 32) ? 1.f : 0.f,
                                            (m & 64) ? 1.f : 0.f, (m & 128) ? 1.f : 0.f);
                    }
                }
            }
            __syncthreads();
        }

        // ---- dump c1 registers (and tsum on iter 0) to LDS
        if (t >= 256) {
#pragma unroll
            for (int k = 0; k < KC; ++k)
                c1o[k * PADD + q] = c1r[k];
            if (it == 0) tsum[q] = treg;
        }
        __syncthreads();

        // ---- normalize: wave r -> row r (= 2k+cc)
        {
            const int k = wave >> 1, cc = wave & 1;
            float vals[12];
            float ss = 0.f;
#pragma unroll
            for (int j = 0; j < 12; ++j) {
                int d = lane + 64 * j;
                float c1v = c1o[k * PADD + d];
                float v = cc ? c1v : (tsum[d] - c1v);
                vals[j] = v;
                ss = fmaf(v, v, ss);
            }
            ss = waveReduceSum(ss);
            float iv = 1.0f / fmaxf(sqrtf(ss), 1e-12f);
#pragma unroll
            for (int j = 0; j < 12; ++j)
                cent[wave][lane + 64 * j] = vals[j] * iv;
        }
        __syncthreads();   // cent ready; bufs free for next iter's staging
    }

    // ---- scatter: vc[idx,0,0] += centroids_final[b,k,0,0] (c0 row, element 0)
    if (t < KC) {
        atomicAdd(delta + sidx[t], cent[2 * t][0]);
    }
}

__global__ __launch_bounds__(1024) void vcnorm_kernel(
    const float* __restrict__ vc,
    const float* __restrict__ delta,
    float* __restrict__ out)          // (V, 2, D)
{
    const int t = threadIdx.x;
    const int lane = t & 63;
    const int wave = t >> 6;
    const int r = blockIdx.x * 16 + wave;     // row in [0, 2V)
    if (r >= 2 * VV) return;
    const int v = r >> 1;
    const int c = r & 1;
    const float* src = vc + (size_t)r * DD;
    float4 x[3];
#pragma unroll
    for (int j = 0; j < 3; ++j)
        x[j] = *(const float4*)(src + (lane + 64 * j) * 4);
    if (c == 0 && lane == 0) x[0].x += delta[v];
    float ss = 0.f;
#pragma unroll
    for (int j = 0; j < 3; ++j)
        ss += x[j].x * x[j].x + x[j].y * x[j].y + x[j].z * x[j].z + x[j].w * x[j].w;
    ss = waveReduceSum(ss);
    float iv = 1.0f / fmaxf(sqrtf(ss), 1e-12f);
    float* dst = out + (size_t)r * DD;
#pragma unroll
    for (int j = 0; j < 3; ++j) {
        float4 y = make_float4(x[j].x * iv, x[j].y * iv, x[j].z * iv, x[j].w * iv);
        *(float4*)(dst + (lane + 64 * j) * 4) = y;
    }
}

extern "C" void kernel_launch(void* const* d_in, const int* in_sizes, int n_in,
                              void* d_out, int out_size, void* d_ws, size_t ws_size,
                              hipStream_t stream) {
    const float* tokens = (const float*)d_in[0];
    const float* vc     = (const float*)d_in[1];
    const int*   topk   = (const int*)d_in[2];
    float* out          = (float*)d_out;
    float* assignments  = out;                                   // B*NT*KC floats
    float* vcnew        = out + (size_t)BB * NT * KC;            // V*2*D floats
    float* delta        = (float*)d_ws;                          // V floats

    hipMemsetAsync(delta, 0, VV * sizeof(float), stream);
    hipLaunchKernelGGL(kmeans_kernel, dim3(BB), dim3(1024), 0, stream,
                       tokens, vc, topk, assignments, delta);
    hipLaunchKernelGGL(vcnorm_kernel, dim3((2 * VV + 15) / 16), dim3(1024), 0, stream,
                       vc, delta, vcnew);
}

// Round 4
// 857.325 us; speedup vs baseline: 1.2913x; 1.2913x over previous
//
#include <hip/hip_runtime.h>
#include <hip/hip_bf16.h>

#define BB 256
#define NN 257
#define NT 256   // tokens per batch (N-1)
#define DD 768
#define KC 8     // K clusters
#define VV 10000
#define ITERS 4

#define CHD 64               // dims per staged chunk
#define NCH (DD / CHD)       // 12 chunks per sim sweep
#define CF4 (CHD / 4)        // 16 float4 per token per chunk
#define CSTR 193             // cent row stride in float4 (772 dwords)

__device__ __forceinline__ float waveReduceSum(float v) {
#pragma unroll
    for (int off = 32; off > 0; off >>= 1)
        v += __shfl_xor(v, off, 64);
    return v;
}

__device__ __forceinline__ float dot4chain(float4 a, float4 c, float acc) {
    // exact chain from rounds 1-2 (x,y,z,w ascending)
    return fmaf(a.w, c.w, fmaf(a.z, c.z, fmaf(a.y, c.y, fmaf(a.x, c.x, acc))));
}

// One block (1024 threads, 16 waves) per batch. Structure = round 2 (symmetric:
// every thread runs a full (token, row-group) sim chain, exact round-1 fp order)
// but the sim phase reads token data from LDS, staged 64-dims-at-a-time for all
// 256 tokens with coalesced float4 global loads (register-prefetched across the
// consume step). Token chunk uses an XOR-swizzled float4 layout so both the
// staging writes and the lane-per-token b128 reads are bank-conflict-free.
// Acc + norm phases are verbatim round 2; tsum folded into iter-0 acc.
__global__ __launch_bounds__(1024) void kmeans_kernel(
    const float* __restrict__ tokens,
    const float* __restrict__ vc,
    const int* __restrict__ topk,
    float* __restrict__ out_assign,   // (B, 256, 8) float
    float* __restrict__ delta)        // (V) float accumulators (pre-zeroed)
{
    __shared__ float4 cent4[16 * CSTR];       // 49.4 KB  normalized centroids (row = 2k+c)
    __shared__ float4 tbuf4[NT * CF4];        // 64 KB    swizzled token chunk (64 dims x 256 tok)
    __shared__ float  c1buf[KC][DD];          // 24 KB
    __shared__ float  tsum[DD];               // 3 KB
    __shared__ unsigned maskA[NT];            // 1 KB
    __shared__ unsigned char maskp[4][NT];    // 1 KB
    __shared__ int sidx[KC];

    float* centf = (float*)cent4;

    const int b = blockIdx.x;
    const int t = threadIdx.x;
    const int lane = t & 63;
    const int wave = t >> 6;

    if (t < KC) sidx[t] = topk[b * KC + t];
    __syncthreads();

    // ---- gather + L2-normalize 16 initial centroid rows: wave r -> row r
    {
        const int r = wave;
        const int k = r >> 1, c = r & 1;
        const float* src = vc + ((size_t)sidx[k] * 2 + c) * DD;
        float vals[12];
        float ss = 0.f;
#pragma unroll
        for (int j = 0; j < 12; ++j) {
            vals[j] = src[lane + 64 * j];
            ss = fmaf(vals[j], vals[j], ss);
        }
        ss = waveReduceSum(ss);
        float iv = 1.0f / fmaxf(sqrtf(ss), 1e-12f);
#pragma unroll
        for (int j = 0; j < 12; ++j)
            centf[r * 772 + lane + 64 * j] = vals[j] * iv;
    }
    __syncthreads();

    const float* tpb = tokens + ((size_t)b * NN + 1) * DD;

    // sim roles: thread = (token, row-group of 4)
    const int tok = t & 255;
    const int g   = t >> 8;
    const int s7  = tok & 7;
    // staging roles: thread stages 4 float4s: tokens stok+64p, f4-col sq
    const int stok = t >> 4;      // 0..63
    const int sq   = t & 15;      // 0..15

    for (int it = 0; it < ITERS; ++it) {
        float acc[4] = {0.f, 0.f, 0.f, 0.f};
        float4 st[4];

        // ---- prologue: stage chunk 0
#pragma unroll
        for (int p = 0; p < 4; ++p)
            st[p] = *(const float4*)(tpb + (size_t)(64 * p + stok) * DD + 4 * sq);
#pragma unroll
        for (int p = 0; p < 4; ++p)
            tbuf4[((64 * p + stok) << 4) + (sq ^ (stok & 7))] = st[p];
        __syncthreads();

        for (int cix = 0; cix < NCH; ++cix) {
            // issue next chunk's global loads (latency hidden by consume below)
            if (cix + 1 < NCH) {
#pragma unroll
                for (int p = 0; p < 4; ++p)
                    st[p] = *(const float4*)(tpb + (size_t)(64 * p + stok) * DD
                                             + (cix + 1) * CHD + 4 * sq);
            }
            // ---- consume chunk cix: advance the 4 row chains over 64 dims
            {
                const float4* tb = tbuf4 + (tok << 4);
                const float4* cr = cent4 + (g * 4) * CSTR + (cix << 4);
#pragma unroll
                for (int j4 = 0; j4 < CF4; ++j4) {
                    float4 a  = tb[j4 ^ s7];            // conflict-free swizzled b128
                    float4 c0 = cr[j4];                 // wave-uniform broadcasts
                    float4 c1 = cr[CSTR + j4];
                    float4 c2 = cr[2 * CSTR + j4];
                    float4 c3 = cr[3 * CSTR + j4];
                    acc[0] = dot4chain(a, c0, acc[0]);
                    acc[1] = dot4chain(a, c1, acc[1]);
                    acc[2] = dot4chain(a, c2, acc[2]);
                    acc[3] = dot4chain(a, c3, acc[3]);
                }
            }
            __syncthreads();                 // all reads of tbuf done
            if (cix + 1 < NCH) {
#pragma unroll
                for (int p = 0; p < 4; ++p)
                    tbuf4[((64 * p + stok) << 4) + (sq ^ (stok & 7))] = st[p];
            }
            __syncthreads();                 // writes visible
        }

        // ---- masks (exact round-2 path)
        unsigned m2 = 0;
        if (acc[1] > acc[0]) m2 |= 1u;       // cluster 2g   (ties -> 0)
        if (acc[3] > acc[2]) m2 |= 2u;       // cluster 2g+1
        maskp[g][tok] = (unsigned char)m2;
        __syncthreads();

        if (t < NT) {
            unsigned m = (unsigned)maskp[0][t]
                       | ((unsigned)maskp[1][t] << 2)
                       | ((unsigned)maskp[2][t] << 4)
                       | ((unsigned)maskp[3][t] << 6);
            maskA[t] = m;
            if (it == ITERS - 1) {
                float4* op = (float4*)(out_assign + ((size_t)b * NT + t) * KC);
                op[0] = make_float4((m & 1) ? 1.f : 0.f, (m & 2) ? 1.f : 0.f,
                                    (m & 4) ? 1.f : 0.f, (m & 8) ? 1.f : 0.f);
                op[1] = make_float4((m & 16) ? 1.f : 0.f, (m & 32) ? 1.f : 0.f,
                                    (m & 64) ? 1.f : 0.f, (m & 128) ? 1.f : 0.f);
            }
        }
        __syncthreads();

        // ============ accumulate phase (verbatim round 2, + tsum fold) ============
        {
            const int tt = t & 255;
            float c1[3][2] = {{0.f, 0.f}, {0.f, 0.f}, {0.f, 0.f}};
            float tr0 = 0.f, tr1 = 0.f, tr2 = 0.f;
            for (int n = 0; n < NT; ++n) {
                unsigned mn = maskA[n];
                const float* rn = tpb + (size_t)n * DD;
                float v0 = rn[tt], v1 = rn[tt + 256], v2 = rn[tt + 512];  // coalesced
#pragma unroll
                for (int kk = 0; kk < 2; ++kk) {
                    bool on = (mn >> (2 * g + kk)) & 1;
                    c1[0][kk] += on ? v0 : 0.f;
                    c1[1][kk] += on ? v1 : 0.f;
                    c1[2][kk] += on ? v2 : 0.f;
                }
                if (it == 0 && g == 0) { tr0 += v0; tr1 += v1; tr2 += v2; }
            }
#pragma unroll
            for (int i = 0; i < 3; ++i)
#pragma unroll
                for (int kk = 0; kk < 2; ++kk)
                    c1buf[2 * g + kk][tt + 256 * i] = c1[i][kk];
            if (it == 0 && g == 0) {
                tsum[tt] = tr0; tsum[tt + 256] = tr1; tsum[tt + 512] = tr2;
            }
        }
        __syncthreads();

        // ============ normalize phase: wave r -> row r (= 2k+cc) ============
        {
            const int k = wave >> 1, cc = wave & 1;
            float vals[12];
            float ss = 0.f;
#pragma unroll
            for (int j = 0; j < 12; ++j) {
                int d = lane + 64 * j;
                float c1v = c1buf[k][d];
                float v = cc ? c1v : (tsum[d] - c1v);
                vals[j] = v;
                ss = fmaf(v, v, ss);
            }
            ss = waveReduceSum(ss);
            float iv = 1.0f / fmaxf(sqrtf(ss), 1e-12f);
#pragma unroll
            for (int j = 0; j < 12; ++j)
                centf[wave * 772 + lane + 64 * j] = vals[j] * iv;
        }
        __syncthreads();
    }

    // ---- scatter: vc[idx,0,0] += centroids_final[b,k,0,0] (c0 row, element 0)
    if (t < KC) {
        atomicAdd(delta + sidx[t], centf[(2 * t) * 772]);
    }
}

__global__ __launch_bounds__(1024) void vcnorm_kernel(
    const float* __restrict__ vc,
    const float* __restrict__ delta,
    float* __restrict__ out)          // (V, 2, D)
{
    const int t = threadIdx.x;
    const int lane = t & 63;
    const int wave = t >> 6;
    const int r = blockIdx.x * 16 + wave;     // row in [0, 2V)
    if (r >= 2 * VV) return;
    const int v = r >> 1;
    const int c = r & 1;
    const float* src = vc + (size_t)r * DD;
    float4 x[3];
#pragma unroll
    for (int j = 0; j < 3; ++j)
        x[j] = *(const float4*)(src + (lane + 64 * j) * 4);
    if (c == 0 && lane == 0) x[0].x += delta[v];
    float ss = 0.f;
#pragma unroll
    for (int j = 0; j < 3; ++j)
        ss += x[j].x * x[j].x + x[j].y * x[j].y + x[j].z * x[j].z + x[j].w * x[j].w;
    ss = waveReduceSum(ss);
    float iv = 1.0f / fmaxf(sqrtf(ss), 1e-12f);
    float* dst = out + (size_t)r * DD;
#pragma unroll
    for (int j = 0; j < 3; ++j) {
        float4 y = make_float4(x[j].x * iv, x[j].y * iv, x[j].z * iv, x[j].w * iv);
        *(float4*)(dst + (lane + 64 * j) * 4) = y;
    }
}

extern "C" void kernel_launch(void* const* d_in, const int* in_sizes, int n_in,
                              void* d_out, int out_size, void* d_ws, size_t ws_size,
                              hipStream_t stream) {
    const float* tokens = (const float*)d_in[0];
    const float* vc     = (const float*)d_in[1];
    const int*   topk   = (const int*)d_in[2];
    float* out          = (float*)d_out;
    float* assignments  = out;                                   // B*NT*KC floats
    float* vcnew        = out + (size_t)BB * NT * KC;            // V*2*D floats
    float* delta        = (float*)d_ws;                          // V floats

    hipMemsetAsync(delta, 0, VV * sizeof(float), stream);
    hipLaunchKernelGGL(kmeans_kernel, dim3(BB), dim3(1024), 0, stream,
                       tokens, vc, topk, assignments, delta);
    hipLaunchKernelGGL(vcnorm_kernel, dim3((2 * VV + 15) / 16), dim3(1024), 0, stream,
                       vc, delta, vcnew);
}

// Round 5
// 698.972 us; speedup vs baseline: 1.5838x; 1.2266x over previous
//
#include <hip/hip_runtime.h>
#include <hip/hip_bf16.h>

#define BB 256
#define NN 257
#define NT 256   // tokens per batch (N-1)
#define DD 768
#define KC 8     // K clusters
#define VV 10000
#define ITERS 4

#define CHD 32               // dims per staged chunk (= 128 B = 1 cache line per token)
#define NCH (DD / CHD)       // 24 chunks per sim sweep
#define CF4 (CHD / 4)        // 8 float4 per token per chunk
#define CSTR 193             // cent row stride in float4 (772 dwords)

__device__ __forceinline__ float waveReduceSum(float v) {
#pragma unroll
    for (int off = 32; off > 0; off >>= 1)
        v += __shfl_xor(v, off, 64);
    return v;
}

__device__ __forceinline__ float dot4chain(float4 a, float4 c, float acc) {
    // exact chain from rounds 1-4 (x,y,z,w ascending)
    return fmaf(a.w, c.w, fmaf(a.z, c.z, fmaf(a.y, c.y, fmaf(a.x, c.x, acc))));
}

// Async global->LDS DMA, 16 B per lane, LDS dest = wave-uniform base + lane*16.
__device__ __forceinline__ void gld16(const float* g, void* lds) {
    __builtin_amdgcn_global_load_lds(
        (const __attribute__((address_space(1))) void*)g,
        (__attribute__((address_space(3))) void*)lds,
        16, 0, 0);
}

// One block (1024 threads, 16 waves) per batch. Sim phase streams tokens
// 32-dims-at-a-time for all 256 tokens into a double-buffered LDS chunk via
// global_load_lds DMA (no staging VGPRs -> no scratch spills), one barrier per
// chunk (issue c+1, consume c, barrier drains vmcnt). The bank swizzle is
// applied on the GLOBAL side (lane -> token slot>>3, col (slot&7)^(tok&7)) so
// sim's lane-per-token b128 reads hit 8 distinct bank-quads per 8-lane group
// (conflict-free) while each token-chunk is exactly one 128 B line in HBM.
// All per-value fp chains are bit-identical to the round-1/2/4 kernels that
// passed: sim j-ascending fma chain, acc/tsum n-ascending adds, wave-per-row
// norms with 64-lane butterfly.
__global__ __launch_bounds__(1024, 4) void kmeans_kernel(
    const float* __restrict__ tokens,
    const float* __restrict__ vc,
    const int* __restrict__ topk,
    float* __restrict__ out_assign,   // (B, 256, 8) float
    float* __restrict__ delta)        // (V) float accumulators (pre-zeroed)
{
    __shared__ float4 cent4[16 * CSTR];       // 48.2 KB  normalized centroids (row = 2k+c)
    __shared__ float4 tbuf4[2 * NT * CF4];    // 64 KB    double-buffered swizzled chunks
    __shared__ float  c1buf[KC][DD];          // 24 KB
    __shared__ float  tsum[DD];               // 3 KB
    __shared__ unsigned maskA[NT];            // 1 KB
    __shared__ unsigned char maskp[4][NT];    // 1 KB
    __shared__ int sidx[KC];

    float* centf = (float*)cent4;

    const int b = blockIdx.x;
    const int t = threadIdx.x;
    const int lane = t & 63;
    const int wave = t >> 6;

    if (t < KC) sidx[t] = topk[b * KC + t];
    __syncthreads();

    // ---- gather + L2-normalize 16 initial centroid rows: wave r -> row r
    {
        const int r = wave;
        const int k = r >> 1, c = r & 1;
        const float* src = vc + ((size_t)sidx[k] * 2 + c) * DD;
        float vals[12];
        float ss = 0.f;
#pragma unroll
        for (int j = 0; j < 12; ++j) {
            vals[j] = src[lane + 64 * j];
            ss = fmaf(vals[j], vals[j], ss);
        }
        ss = waveReduceSum(ss);
        float iv = 1.0f / fmaxf(sqrtf(ss), 1e-12f);
#pragma unroll
        for (int j = 0; j < 12; ++j)
            centf[r * 772 + lane + 64 * j] = vals[j] * iv;
    }
    __syncthreads();

    const float* tpb = tokens + ((size_t)b * NN + 1) * DD;

    // sim roles: thread = (token, row-group of 4)
    const int tok = t & 255;
    const int g   = t >> 8;
    const int s7  = tok & 7;

    // DMA lane roles: wave handles chunk slots [wave*128, wave*128+128)
    // slot -> token slot>>3, physical f4 q = slot&7, global col = q ^ (tok&7)
    const int slotA = wave * 128 + lane;         // load 0
    const int slotB = slotA + 64;                // load 1
    const float* gbaseA = tpb + (size_t)(slotA >> 3) * DD + 4 * ((slotA & 7) ^ ((slotA >> 3) & 7));
    const float* gbaseB = tpb + (size_t)(slotB >> 3) * DD + 4 * ((slotB & 7) ^ ((slotB >> 3) & 7));

    for (int it = 0; it < ITERS; ++it) {
        float acc[4] = {0.f, 0.f, 0.f, 0.f};

        // prologue: DMA chunk 0 into buffer 0
        gld16(gbaseA, (void*)(tbuf4 + wave * 128));
        gld16(gbaseB, (void*)(tbuf4 + wave * 128 + 64));

        for (int cix = 0; cix < NCH; ++cix) {
            __syncthreads();   // drains vmcnt -> buf[cix&1] complete & visible
            if (cix + 1 < NCH) {
                const int nb = (cix + 1) & 1;
                gld16(gbaseA + (cix + 1) * CHD, (void*)(tbuf4 + nb * 2048 + wave * 128));
                gld16(gbaseB + (cix + 1) * CHD, (void*)(tbuf4 + nb * 2048 + wave * 128 + 64));
            }
            // ---- consume chunk cix: advance the 4 row chains over 32 dims
            {
                const float4* tb = tbuf4 + (cix & 1) * 2048 + (tok << 3);
                const float4* cr = cent4 + (g * 4) * CSTR + (cix << 3);
#pragma unroll
                for (int j4 = 0; j4 < CF4; ++j4) {
                    float4 a  = tb[j4 ^ s7];            // conflict-free swizzled b128
                    float4 c0 = cr[j4];                 // wave-uniform broadcasts
                    float4 c1 = cr[CSTR + j4];
                    float4 c2 = cr[2 * CSTR + j4];
                    float4 c3 = cr[3 * CSTR + j4];
                    acc[0] = dot4chain(a, c0, acc[0]);
                    acc[1] = dot4chain(a, c1, acc[1]);
                    acc[2] = dot4chain(a, c2, acc[2]);
                    acc[3] = dot4chain(a, c3, acc[3]);
                }
            }
        }

        // ---- masks (exact round-2/4 path)
        unsigned m2 = 0;
        if (acc[1] > acc[0]) m2 |= 1u;       // cluster 2g   (ties -> 0)
        if (acc[3] > acc[2]) m2 |= 2u;       // cluster 2g+1
        maskp[g][tok] = (unsigned char)m2;
        __syncthreads();

        if (t < NT) {
            unsigned m = (unsigned)maskp[0][t]
                       | ((unsigned)maskp[1][t] << 2)
                       | ((unsigned)maskp[2][t] << 4)
                       | ((unsigned)maskp[3][t] << 6);
            maskA[t] = m;
            if (it == ITERS - 1) {
                float4* op = (float4*)(out_assign + ((size_t)b * NT + t) * KC);
                op[0] = make_float4((m & 1) ? 1.f : 0.f, (m & 2) ? 1.f : 0.f,
                                    (m & 4) ? 1.f : 0.f, (m & 8) ? 1.f : 0.f);
                op[1] = make_float4((m & 16) ? 1.f : 0.f, (m & 32) ? 1.f : 0.f,
                                    (m & 64) ? 1.f : 0.f, (m & 128) ? 1.f : 0.f);
            }
        }
        __syncthreads();

        // ============ accumulate phase (verbatim round 4, + tsum fold) ============
        {
            const int tt = t & 255;
            float c1[3][2] = {{0.f, 0.f}, {0.f, 0.f}, {0.f, 0.f}};
            float tr0 = 0.f, tr1 = 0.f, tr2 = 0.f;
            for (int n = 0; n < NT; ++n) {
                unsigned mn = maskA[n];
                const float* rn = tpb + (size_t)n * DD;
                float v0 = rn[tt], v1 = rn[tt + 256], v2 = rn[tt + 512];  // coalesced
#pragma unroll
                for (int kk = 0; kk < 2; ++kk) {
                    bool on = (mn >> (2 * g + kk)) & 1;
                    c1[0][kk] += on ? v0 : 0.f;
                    c1[1][kk] += on ? v1 : 0.f;
                    c1[2][kk] += on ? v2 : 0.f;
                }
                if (it == 0 && g == 0) { tr0 += v0; tr1 += v1; tr2 += v2; }
            }
#pragma unroll
            for (int i = 0; i < 3; ++i)
#pragma unroll
                for (int kk = 0; kk < 2; ++kk)
                    c1buf[2 * g + kk][tt + 256 * i] = c1[i][kk];
            if (it == 0 && g == 0) {
                tsum[tt] = tr0; tsum[tt + 256] = tr1; tsum[tt + 512] = tr2;
            }
        }
        __syncthreads();

        // ============ normalize phase: wave r -> row r (= 2k+cc) ============
        {
            const int k = wave >> 1, cc = wave & 1;
            float vals[12];
            float ss = 0.f;
#pragma unroll
            for (int j = 0; j < 12; ++j) {
                int d = lane + 64 * j;
                float c1v = c1buf[k][d];
                float v = cc ? c1v : (tsum[d] - c1v);
                vals[j] = v;
                ss = fmaf(v, v, ss);
            }
            ss = waveReduceSum(ss);
            float iv = 1.0f / fmaxf(sqrtf(ss), 1e-12f);
#pragma unroll
            for (int j = 0; j < 12; ++j)
                centf[wave * 772 + lane + 64 * j] = vals[j] * iv;
        }
        __syncthreads();   // cent ready; tbuf free for next iter's staging
    }

    // ---- scatter: vc[idx,0,0] += centroids_final[b,k,0,0] (c0 row, element 0)
    if (t < KC) {
        atomicAdd(delta + sidx[t], centf[(2 * t) * 772]);
    }
}

__global__ __launch_bounds__(1024) void vcnorm_kernel(
    const float* __restrict__ vc,
    const float* __restrict__ delta,
    float* __restrict__ out)          // (V, 2, D)
{
    const int t = threadIdx.x;
    const int lane = t & 63;
    const int wave = t >> 6;
    const int r = blockIdx.x * 16 + wave;     // row in [0, 2V)
    if (r >= 2 * VV) return;
    const int v = r >> 1;
    const int c = r & 1;
    const float* src = vc + (size_t)r * DD;
    float4 x[3];
#pragma unroll
    for (int j = 0; j < 3; ++j)
        x[j] = *(const float4*)(src + (lane + 64 * j) * 4);
    if (c == 0 && lane == 0) x[0].x += delta[v];
    float ss = 0.f;
#pragma unroll
    for (int j = 0; j < 3; ++j)
        ss += x[j].x * x[j].x + x[j].y * x[j].y + x[j].z * x[j].z + x[j].w * x[j].w;
    ss = waveReduceSum(ss);
    float iv = 1.0f / fmaxf(sqrtf(ss), 1e-12f);
    float* dst = out + (size_t)r * DD;
#pragma unroll
    for (int j = 0; j < 3; ++j) {
        float4 y = make_float4(x[j].x * iv, x[j].y * iv, x[j].z * iv, x[j].w * iv);
        *(float4*)(dst + (lane + 64 * j) * 4) = y;
    }
}

extern "C" void kernel_launch(void* const* d_in, const int* in_sizes, int n_in,
                              void* d_out, int out_size, void* d_ws, size_t ws_size,
                              hipStream_t stream) {
    const float* tokens = (const float*)d_in[0];
    const float* vc     = (const float*)d_in[1];
    const int*   topk   = (const int*)d_in[2];
    float* out          = (float*)d_out;
    float* assignments  = out;                                   // B*NT*KC floats
    float* vcnew        = out + (size_t)BB * NT * KC;            // V*2*D floats
    float* delta        = (float*)d_ws;                          // V floats

    hipMemsetAsync(delta, 0, VV * sizeof(float), stream);
    hipLaunchKernelGGL(kmeans_kernel, dim3(BB), dim3(1024), 0, stream,
                       tokens, vc, topk, assignments, delta);
    hipLaunchKernelGGL(vcnorm_kernel, dim3((2 * VV + 15) / 16), dim3(1024), 0, stream,
                       vc, delta, vcnew);
}